// Round 10
// baseline (224.760 us; speedup 1.0000x reference)
//
#include <hip/hip_runtime.h>
#include <hip/hip_bf16.h>
#include <math.h>

#define B_ 4
#define T_ 2048
#define C_ 1024
#define M_ (B_*T_)   // 8192 rows

typedef __attribute__((ext_vector_type(8))) __bf16 bf16x8;
typedef __attribute__((ext_vector_type(4))) float floatx4;

// ---------- bf16 helpers ----------
__device__ inline float bf2f(unsigned short u){
    return __uint_as_float(((unsigned)u) << 16);
}
__device__ inline unsigned short f2bf(float f){
    unsigned u = __float_as_uint(f);
    unsigned r = (u + 0x7fffu + ((u >> 16) & 1u)) >> 16;   // RNE
    return (unsigned short)r;
}

// ---------- async global->LDS, 16 B per lane, wave-uniform LDS base ----------
__device__ inline void llds16(const unsigned short* g, unsigned short* lds){
    __builtin_amdgcn_global_load_lds(
        (const __attribute__((address_space(1))) unsigned int*)g,
        (__attribute__((address_space(3))) unsigned int*)(unsigned int)(uintptr_t)lds,
        16, 0, 0);
}

// ---------- fp32 -> bf16 cast, all four tensors in one launch ----------
#define NX_ (M_*C_/4)
#define NW_ (C_*C_/4)
__global__ __launch_bounds__(256) void cast_all(
    const float* __restrict__ x, const float* __restrict__ wq,
    const float* __restrict__ wk, const float* __restrict__ wv,
    unsigned short* __restrict__ xb, unsigned short* __restrict__ wb)
{
    int i = blockIdx.x * 256 + threadIdx.x;
    const float* src; unsigned short* dst; int idx;
    if (i < NX_){ src = x; dst = xb; idx = i; }
    else {
        i -= NX_;
        int w = i / NW_; idx = i - w * NW_;
        src = (w == 0) ? wq : ((w == 1) ? wk : wv);
        dst = wb + (size_t)w * C_ * C_;
    }
    float4 v = ((const float4*)src)[idx];
    ((ushort4*)dst)[idx] = make_ushort4(f2bf(v.x), f2bf(v.y), f2bf(v.z), f2bf(v.w));
}

// ---------- MFMA tile core, wave tile WM x WN (NT GEMM) ----------
// 256 thr = 4 waves in 2x2 -> block tile (2*WM) x (2*WN). 16x16x32 MFMAs.
// BK=64, LDS rows of 64 ushorts, XOR-swizzled chunk layout (row r chunk c at
// position c^(r&7)): staging lane l covers LDS (row l>>3, pos l&7) -> loads
// global chunk (l&7)^((l>>3)&7); fragment read chunk ((ks>>3)+fq)^(fr&7).
// Measured 0 bank conflicts (round 6/7); 32x32 MFMA variant regressed (round 8).
// RS: accumulate per-lane row sums of A fragments (pv's softmax denominator).
template<int WM, int WN, bool RS>
__device__ inline void gemm_core(const unsigned short* __restrict__ A,
                                 const unsigned short* __restrict__ Bm,
                                 int lda, int ldb, int m0, int n0, int kTiles,
                                 unsigned short* As, unsigned short* Bs,
                                 floatx4 (*acc)[WN/16], float* rs)
{
    const int tid  = threadIdx.x;
    const int lane = tid & 63;
    const int wave = tid >> 6;            // 0..3
    const int wm = (wave >> 1) * WM;
    const int wn = (wave & 1) * WN;
    const int fr = lane & 15;
    const int fq = lane >> 4;
    const int cxor = fr & 7;
    const int sr = lane >> 3;
    const int sc = ((lane & 7) ^ ((lane >> 3) & 7)) * 8;   // swizzled source chunk

    const unsigned short* gA = A  + (size_t)(m0 + wave * (WM/2) + sr) * lda + sc;
    const unsigned short* gB = Bm + (size_t)(n0 + wave * (WN/2) + sr) * ldb + sc;
    unsigned short* ldsA = As + wave * (WM/2) * 64;
    unsigned short* ldsB = Bs + wave * (WN/2) * 64;

    for (int kt = 0; kt < kTiles; kt++){
        const int k0 = kt * 64;
        __syncthreads();                  // prior iter's LDS reads complete
        #pragma unroll
        for (int i = 0; i < WM/16; i++)
            llds16(gA + (size_t)(i * 8) * lda + k0, ldsA + i * 8 * 64);
        #pragma unroll
        for (int i = 0; i < WN/16; i++)
            llds16(gB + (size_t)(i * 8) * ldb + k0, ldsB + i * 8 * 64);
        __syncthreads();                  // drains vmcnt -> staged data visible
        #pragma unroll
        for (int ks = 0; ks < 64; ks += 32){
            const int cpos = (((ks >> 3) + fq) ^ cxor) * 8;
            bf16x8 af[WM/16], bv[WN/16];
            #pragma unroll
            for (int i = 0; i < WM/16; i++)
                af[i] = *(const bf16x8*)(As + (wm + i*16 + fr) * 64 + cpos);
            #pragma unroll
            for (int j = 0; j < WN/16; j++)
                bv[j] = *(const bf16x8*)(Bs + (wn + j*16 + fr) * 64 + cpos);
            #pragma unroll
            for (int i = 0; i < WM/16; i++)
                #pragma unroll
                for (int j = 0; j < WN/16; j++)
                    acc[i][j] = __builtin_amdgcn_mfma_f32_16x16x32_bf16(af[i], bv[j], acc[i][j], 0, 0, 0);
            if (RS){
                #pragma unroll
                for (int i = 0; i < WM/16; i++)
                    #pragma unroll
                    for (int e = 0; e < 8; e++)
                        rs[i] += (float)af[i][e];
            }
        }
    }
}

// ---------- QKV projection: y = x @ W^T, bf16 out. z=0 Q, z=1 K (row-major), z=2 V^T ----------
// 1-D grid 1536; XCD = id%8 (m09). XCD k owns m-tiles [8k,8k+8) x all n x all z
// -> per-XCD fill = x/8 + W = 8.4 MB (measured FETCH 178->41.5 MB, r9).
__global__ __launch_bounds__(256, 4) void proj_gemm(
    const unsigned short* __restrict__ xb,
    const unsigned short* __restrict__ Wb,   // [3][C_][C_]
    unsigned short* __restrict__ Qb, unsigned short* __restrict__ Kb,
    unsigned short* __restrict__ Vt)
{
    __shared__ unsigned short As[128 * 64];
    __shared__ unsigned short Bs[128 * 64];
    const int L = blockIdx.x;
    const int k = L & 7, j = L >> 3;          // j in [0,192)
    const int m0 = (k * 8 + (j & 7)) * 128;
    const int n0 = ((j >> 3) & 7) * 128;
    const int z  = j >> 6;
    const unsigned short* W = Wb + (size_t)z * C_ * C_;

    floatx4 acc[4][4];
    #pragma unroll
    for (int i = 0; i < 4; i++)
        #pragma unroll
        for (int jj = 0; jj < 4; jj++) acc[i][jj] = (floatx4){0.f,0.f,0.f,0.f};
    gemm_core<64, 64, false>(xb, W, C_, C_, m0, n0, C_ / 64, As, Bs, acc, nullptr);

    const int lane = threadIdx.x & 63, wave = threadIdx.x >> 6;
    const int wm = (wave >> 1) * 64, wn = (wave & 1) * 64;
    const int fr = lane & 15, fq = lane >> 4;

    if (z < 2){
        unsigned short* Y = z ? Kb : Qb;
        #pragma unroll
        for (int i = 0; i < 4; i++)
            #pragma unroll
            for (int jj = 0; jj < 4; jj++)
                #pragma unroll
                for (int r = 0; r < 4; r++){
                    int row = m0 + wm + i*16 + fq*4 + r;
                    int col = n0 + wn + jj*16 + fr;
                    Y[(size_t)row * C_ + col] = f2bf(acc[i][jj][r]);
                }
    } else {
        // V^T[b][d][t]; 4 acc regs = 4 consecutive t -> packed ushort4 store
        #pragma unroll
        for (int i = 0; i < 4; i++)
            #pragma unroll
            for (int jj = 0; jj < 4; jj++){
                int row = m0 + wm + i*16 + fq*4;         // token index
                int col = n0 + wn + jj*16 + fr;          // d
                int b = row / T_, t = row % T_;
                ushort4 o = make_ushort4(f2bf(acc[i][jj][0]), f2bf(acc[i][jj][1]),
                                         f2bf(acc[i][jj][2]), f2bf(acc[i][jj][3]));
                *(ushort4*)&Vt[(size_t)b * C_ * T_ + (size_t)col * T_ + t] = o;
            }
    }
}

// ---------- S = Q K^T, causal mask + unnormalized exp -> P (bf16) ----------
// 64(t) x 128(s) tiles -> grid 1088 = 8 XCDs x 136 blocks = 4.25 blocks/CU
// (round-9's 128x128 gave only 2.1/CU -> latency-bound). XCD k owns ti-pair
// {k,15-k} (score work ti+1+16-ti = 17 s-columns -> balanced); each 128-row
// ti splits into two 64-row halves. Logits bounded -> no max pass.
__global__ __launch_bounds__(256, 4) void score_gemm(
    const unsigned short* __restrict__ Qb, const unsigned short* __restrict__ Kb,
    unsigned short* __restrict__ P)
{
    const int L = blockIdx.x;
    const int k = L & 7, j = L >> 3;          // j in [0,136)
    const int b = j / 34, rem = j % 34;
    const int th = rem & 1, rr = rem >> 1;    // rr in [0,17)
    int ti, si;
    if (rr <= 15 - k){ ti = 15 - k; si = rr; }
    else             { ti = k;      si = rr - (16 - k); }
    const int t0 = ti * 128 + th * 64, s0 = si * 128;

    __shared__ unsigned short As[64 * 64];
    __shared__ unsigned short Bs[128 * 64];
    floatx4 acc[2][4];
    #pragma unroll
    for (int i = 0; i < 2; i++)
        #pragma unroll
        for (int jj = 0; jj < 4; jj++) acc[i][jj] = (floatx4){0.f,0.f,0.f,0.f};
    gemm_core<32, 64, false>(Qb + (size_t)b * T_ * C_, Kb + (size_t)b * T_ * C_,
                             C_, C_, t0, s0, C_ / 64, As, Bs, acc, nullptr);

    const int lane = threadIdx.x & 63, wave = threadIdx.x >> 6;
    const int wm = (wave >> 1) * 32, wn = (wave & 1) * 64;
    const int fr = lane & 15, fq = lane >> 4;
    unsigned short* Pb = P + (size_t)b * T_ * T_;
    const float scale = 0.03125f;        // 1/sqrt(1024)
    #pragma unroll
    for (int i = 0; i < 2; i++)
        #pragma unroll
        for (int jj = 0; jj < 4; jj++)
            #pragma unroll
            for (int r2 = 0; r2 < 4; r2++){
                int t = t0 + wm + i*16 + fq*4 + r2;
                int s = s0 + wn + jj*16 + fr;
                float v = (s <= t) ? __expf(acc[i][jj][r2] * scale) : 0.f;
                Pb[(size_t)t * T_ + s] = f2bf(v);
            }
}

// ---------- O = (P V) / rowsum(P), rowsum computed locally from A fragments ----------
// 128(t) x 64(d) tiles -> grid 1024 = 8 XCDs x 128 blocks = 4 blocks/CU.
// XCD k owns t-tiles {k,15-k}: every CU gets 2 long + 2 short blocks -> per-CU
// work = 2*2(k+1) + 2*2(16-k) = 68 k-tiles uniformly (round-9's 128x128 left
// XCD0 CUs with a 32-tile critical path at 2-way parallelism).
__global__ __launch_bounds__(256, 4) void pv_gemm(
    const unsigned short* __restrict__ P, const unsigned short* __restrict__ Vt,
    float* __restrict__ out)
{
    const int L = blockIdx.x;
    const int k = L & 7, j = L >> 3;          // j in [0,128)
    const int b = j >> 5, r = j & 31;
    const int n0 = (r >> 1) * 64;             // d tile (64 wide)
    const int ti = (r & 1) ? k : (15 - k);
    const int t0 = ti * 128;

    __shared__ unsigned short As[128 * 64];
    __shared__ unsigned short Bs[64 * 64];
    __shared__ float lsum[128];

    floatx4 acc[4][2];
    #pragma unroll
    for (int i = 0; i < 4; i++)
        #pragma unroll
        for (int jj = 0; jj < 2; jj++) acc[i][jj] = (floatx4){0.f,0.f,0.f,0.f};
    float rs[4] = {0.f, 0.f, 0.f, 0.f};
    const int kTiles = (t0 + 128) / 64;  // causal: keys s < t0+128 only
    gemm_core<64, 32, true>(P + (size_t)b * T_ * T_, Vt + (size_t)b * C_ * T_,
                            T_, T_, t0, n0, kTiles, As, Bs, acc, rs);

    const int lane = threadIdx.x & 63, wave = threadIdx.x >> 6;
    const int wm = (wave >> 1) * 64, wn = (wave & 1) * 32;
    const int fr = lane & 15, fq = lane >> 4;

    // rs[i] = partial row sum of P row wm+i*16+fr over this lane's k-slices.
    #pragma unroll
    for (int i = 0; i < 4; i++){
        float v = rs[i];
        v += __shfl_xor(v, 16, 64);
        v += __shfl_xor(v, 32, 64);
        rs[i] = v;
    }
    // Waves sharing wm compute bitwise-identical sums -> benign duplicate write.
    if (fq == 0){
        #pragma unroll
        for (int i = 0; i < 4; i++) lsum[wm + i*16 + fr] = rs[i];
    }
    __syncthreads();

    float* ob = out + (size_t)b * T_ * C_;
    #pragma unroll
    for (int i = 0; i < 4; i++){
        float inv[4];
        #pragma unroll
        for (int r2 = 0; r2 < 4; r2++) inv[r2] = 1.f / lsum[wm + i*16 + fq*4 + r2];
        #pragma unroll
        for (int jj = 0; jj < 2; jj++)
            #pragma unroll
            for (int r2 = 0; r2 < 4; r2++){
                int t = t0 + wm + i*16 + fq*4 + r2;
                int d = n0 + wn + jj*16 + fr;
                ob[(size_t)t * C_ + d] = acc[i][jj][r2] * inv[r2];
            }
    }
}

extern "C" void kernel_launch(void* const* d_in, const int* in_sizes, int n_in,
                              void* d_out, int out_size, void* d_ws, size_t ws_size,
                              hipStream_t stream)
{
    const float* x  = (const float*)d_in[0];
    const float* Wq = (const float*)d_in[1];
    const float* Wk = (const float*)d_in[2];
    const float* Wv = (const float*)d_in[3];
    float* out = (float*)d_out;

    // ws layout (bf16 elems): Qb | Kb | Vt | P. xb/Wb alias P's region
    // (written by cast, read by proj, then overwritten by score_gemm -- stream-ordered).
    unsigned short* Qb = (unsigned short*)d_ws;
    unsigned short* Kb = Qb + (size_t)M_ * C_;
    unsigned short* Vt = Kb + (size_t)M_ * C_;
    unsigned short* P  = Vt + (size_t)M_ * C_;
    unsigned short* xb = P;
    unsigned short* Wb = P + (size_t)M_ * C_;

    cast_all<<<(NX_ + 3 * NW_ + 255) / 256, 256, 0, stream>>>(x, Wq, Wk, Wv, xb, Wb);
    proj_gemm <<<1536, 256, 0, stream>>>(xb, Wb, Qb, Kb, Vt);
    score_gemm<<<1088, 256, 0, stream>>>(Qb, Kb, P);
    pv_gemm   <<<1024, 256, 0, stream>>>(P, Vt, out);
}

// Round 11
// 215.506 us; speedup vs baseline: 1.0429x; 1.0429x over previous
//
#include <hip/hip_runtime.h>
#include <hip/hip_bf16.h>
#include <math.h>

#define B_ 4
#define T_ 2048
#define C_ 1024
#define M_ (B_*T_)   // 8192 rows

typedef __attribute__((ext_vector_type(8))) __bf16 bf16x8;
typedef __attribute__((ext_vector_type(4))) float floatx4;

// ---------- bf16 helpers ----------
__device__ inline float bf2f(unsigned short u){
    return __uint_as_float(((unsigned)u) << 16);
}
__device__ inline unsigned short f2bf(float f){
    unsigned u = __float_as_uint(f);
    unsigned r = (u + 0x7fffu + ((u >> 16) & 1u)) >> 16;   // RNE
    return (unsigned short)r;
}

// ---------- async global->LDS, 16 B per lane, wave-uniform LDS base ----------
__device__ inline void llds16(const unsigned short* g, unsigned short* lds){
    __builtin_amdgcn_global_load_lds(
        (const __attribute__((address_space(1))) unsigned int*)g,
        (__attribute__((address_space(3))) unsigned int*)(unsigned int)(uintptr_t)lds,
        16, 0, 0);
}

// ---------- fp32 -> bf16 cast, all four tensors in one launch ----------
#define NX_ (M_*C_/4)
#define NW_ (C_*C_/4)
__global__ __launch_bounds__(256) void cast_all(
    const float* __restrict__ x, const float* __restrict__ wq,
    const float* __restrict__ wk, const float* __restrict__ wv,
    unsigned short* __restrict__ xb, unsigned short* __restrict__ wb)
{
    int i = blockIdx.x * 256 + threadIdx.x;
    const float* src; unsigned short* dst; int idx;
    if (i < NX_){ src = x; dst = xb; idx = i; }
    else {
        i -= NX_;
        int w = i / NW_; idx = i - w * NW_;
        src = (w == 0) ? wq : ((w == 1) ? wk : wv);
        dst = wb + (size_t)w * C_ * C_;
    }
    float4 v = ((const float4*)src)[idx];
    ((ushort4*)dst)[idx] = make_ushort4(f2bf(v.x), f2bf(v.y), f2bf(v.z), f2bf(v.w));
}

// ---------- MFMA tile core, wave tile WM x WN (NT GEMM) ----------
// 256 thr = 4 waves in 2x2 -> block tile (2*WM) x (2*WN). 16x16x32 MFMAs.
// BK=64, LDS rows of 64 ushorts, XOR-swizzled chunk layout (row r chunk c at
// position c^(r&7)): staging lane l covers LDS (row l>>3, pos l&7) -> loads
// global chunk (l&7)^((l>>3)&7); fragment read chunk ((ks>>3)+fq)^(fr&7).
// Measured 0 bank conflicts (rounds 6/7/9/10); 32x32-MFMA variant regressed (r8).
template<int WM, int WN>
__device__ inline void gemm_core(const unsigned short* __restrict__ A,
                                 const unsigned short* __restrict__ Bm,
                                 int lda, int ldb, int m0, int n0, int kTiles,
                                 unsigned short* As, unsigned short* Bs,
                                 floatx4 (*acc)[WN/16])
{
    const int tid  = threadIdx.x;
    const int lane = tid & 63;
    const int wave = tid >> 6;            // 0..3
    const int wm = (wave >> 1) * WM;
    const int wn = (wave & 1) * WN;
    const int fr = lane & 15;
    const int fq = lane >> 4;
    const int cxor = fr & 7;
    const int sr = lane >> 3;
    const int sc = ((lane & 7) ^ ((lane >> 3) & 7)) * 8;   // swizzled source chunk

    const unsigned short* gA = A  + (size_t)(m0 + wave * (WM/2) + sr) * lda + sc;
    const unsigned short* gB = Bm + (size_t)(n0 + wave * (WN/2) + sr) * ldb + sc;
    unsigned short* ldsA = As + wave * (WM/2) * 64;
    unsigned short* ldsB = Bs + wave * (WN/2) * 64;

    for (int kt = 0; kt < kTiles; kt++){
        const int k0 = kt * 64;
        __syncthreads();                  // prior iter's LDS reads complete
        #pragma unroll
        for (int i = 0; i < WM/16; i++)
            llds16(gA + (size_t)(i * 8) * lda + k0, ldsA + i * 8 * 64);
        #pragma unroll
        for (int i = 0; i < WN/16; i++)
            llds16(gB + (size_t)(i * 8) * ldb + k0, ldsB + i * 8 * 64);
        __syncthreads();                  // drains vmcnt -> staged data visible
        #pragma unroll
        for (int ks = 0; ks < 64; ks += 32){
            const int cpos = (((ks >> 3) + fq) ^ cxor) * 8;
            bf16x8 af[WM/16], bv[WN/16];
            #pragma unroll
            for (int i = 0; i < WM/16; i++)
                af[i] = *(const bf16x8*)(As + (wm + i*16 + fr) * 64 + cpos);
            #pragma unroll
            for (int j = 0; j < WN/16; j++)
                bv[j] = *(const bf16x8*)(Bs + (wn + j*16 + fr) * 64 + cpos);
            #pragma unroll
            for (int i = 0; i < WM/16; i++)
                #pragma unroll
                for (int j = 0; j < WN/16; j++)
                    acc[i][j] = __builtin_amdgcn_mfma_f32_16x16x32_bf16(af[i], bv[j], acc[i][j], 0, 0, 0);
        }
    }
}

// ---------- QKV projection: y = x @ W^T, bf16 out. z=0 Q, z=1 K (row-major), z=2 V^T ----------
// 1-D grid 1536; XCD = id%8 (m09). XCD k owns m-tiles [8k,8k+8) x all n x all z
// -> per-XCD fill = x/8 + W = 8.4 MB (measured FETCH 178->41.5 MB, r9).
__global__ __launch_bounds__(256, 4) void proj_gemm(
    const unsigned short* __restrict__ xb,
    const unsigned short* __restrict__ Wb,   // [3][C_][C_]
    unsigned short* __restrict__ Qb, unsigned short* __restrict__ Kb,
    unsigned short* __restrict__ Vt)
{
    __shared__ unsigned short As[128 * 64];
    __shared__ unsigned short Bs[128 * 64];
    const int L = blockIdx.x;
    const int k = L & 7, j = L >> 3;          // j in [0,192)
    const int m0 = (k * 8 + (j & 7)) * 128;
    const int n0 = ((j >> 3) & 7) * 128;
    const int z  = j >> 6;
    const unsigned short* W = Wb + (size_t)z * C_ * C_;

    floatx4 acc[4][4];
    #pragma unroll
    for (int i = 0; i < 4; i++)
        #pragma unroll
        for (int jj = 0; jj < 4; jj++) acc[i][jj] = (floatx4){0.f,0.f,0.f,0.f};
    gemm_core<64, 64>(xb, W, C_, C_, m0, n0, C_ / 64, As, Bs, acc);

    const int lane = threadIdx.x & 63, wave = threadIdx.x >> 6;
    const int wm = (wave >> 1) * 64, wn = (wave & 1) * 64;
    const int fr = lane & 15, fq = lane >> 4;

    if (z < 2){
        unsigned short* Y = z ? Kb : Qb;
        #pragma unroll
        for (int i = 0; i < 4; i++)
            #pragma unroll
            for (int jj = 0; jj < 4; jj++)
                #pragma unroll
                for (int r = 0; r < 4; r++){
                    int row = m0 + wm + i*16 + fq*4 + r;
                    int col = n0 + wn + jj*16 + fr;
                    Y[(size_t)row * C_ + col] = f2bf(acc[i][jj][r]);
                }
    } else {
        // V^T[b][d][t]; 4 acc regs = 4 consecutive t -> packed ushort4 store
        #pragma unroll
        for (int i = 0; i < 4; i++)
            #pragma unroll
            for (int jj = 0; jj < 4; jj++){
                int row = m0 + wm + i*16 + fq*4;         // token index
                int col = n0 + wn + jj*16 + fr;          // d
                int b = row / T_, t = row % T_;
                ushort4 o = make_ushort4(f2bf(acc[i][jj][0]), f2bf(acc[i][jj][1]),
                                         f2bf(acc[i][jj][2]), f2bf(acc[i][jj][3]));
                *(ushort4*)&Vt[(size_t)b * C_ * T_ + (size_t)col * T_ + t] = o;
            }
    }
}

// ---------- S = Q K^T, causal mask + unnormalized exp -> P (bf16) + fused row-sum ----------
// 64(t) x 128(s) tiles -> grid 1088 = 4.25 blocks/CU; XCD k owns ti-pair {k,15-k}
// (17 s-columns each -> uniform score blocks). Logits bounded (|qk|/32 ~ N(0,1),
// max ~+6 over 16.8M draws) -> no max pass. Row sums accumulate into l via
// per-row atomicAdd (l memset to 0 in stream; r4-measured cheap).
__global__ __launch_bounds__(256, 4) void score_gemm(
    const unsigned short* __restrict__ Qb, const unsigned short* __restrict__ Kb,
    unsigned short* __restrict__ P, float* __restrict__ l)
{
    const int L = blockIdx.x;
    const int k = L & 7, j = L >> 3;          // j in [0,136)
    const int b = j / 34, rem = j % 34;
    const int th = rem & 1, rr = rem >> 1;    // rr in [0,17)
    int ti, si;
    if (rr <= 15 - k){ ti = 15 - k; si = rr; }
    else             { ti = k;      si = rr - (16 - k); }
    const int t0 = ti * 128 + th * 64, s0 = si * 128;

    __shared__ unsigned short As[64 * 64];
    __shared__ unsigned short Bs[128 * 64];
    floatx4 acc[2][4];
    #pragma unroll
    for (int i = 0; i < 2; i++)
        #pragma unroll
        for (int jj = 0; jj < 4; jj++) acc[i][jj] = (floatx4){0.f,0.f,0.f,0.f};
    gemm_core<32, 64>(Qb + (size_t)b * T_ * C_, Kb + (size_t)b * T_ * C_,
                      C_, C_, t0, s0, C_ / 64, As, Bs, acc);

    const int lane = threadIdx.x & 63, wave = threadIdx.x >> 6;
    const int wm = (wave >> 1) * 32, wn = (wave & 1) * 64;
    const int fr = lane & 15, fq = lane >> 4;
    unsigned short* Pb = P + (size_t)b * T_ * T_;
    const float scale = 0.03125f;        // 1/sqrt(1024)
    float rsl[2][4];
    #pragma unroll
    for (int i = 0; i < 2; i++)
        #pragma unroll
        for (int r2 = 0; r2 < 4; r2++) rsl[i][r2] = 0.f;

    #pragma unroll
    for (int i = 0; i < 2; i++)
        #pragma unroll
        for (int jj = 0; jj < 4; jj++)
            #pragma unroll
            for (int r2 = 0; r2 < 4; r2++){
                int t = t0 + wm + i*16 + fq*4 + r2;
                int s = s0 + wn + jj*16 + fr;
                float v = (s <= t) ? __expf(acc[i][jj][r2] * scale) : 0.f;
                rsl[i][r2] += v;
                Pb[(size_t)t * T_ + s] = f2bf(v);
            }
    // reduce across the 16-lane fr group (xor 1..8 stays inside the group),
    // one atomic per (row, wave): row t gets <=34 atomics total -- negligible.
    #pragma unroll
    for (int i = 0; i < 2; i++)
        #pragma unroll
        for (int r2 = 0; r2 < 4; r2++){
            float v = rsl[i][r2];
            v += __shfl_xor(v, 1, 64);
            v += __shfl_xor(v, 2, 64);
            v += __shfl_xor(v, 4, 64);
            v += __shfl_xor(v, 8, 64);
            if (fr == 0){
                int t = t0 + wm + i*16 + fq*4 + r2;
                atomicAdd(&l[(size_t)b * T_ + t], v);
            }
        }
}

// ---------- O = (P V) / l ----------
// Grid 512, UNIFORM-LENGTH blocks: block = (XCD k, b, 64-wide d-tile) processes
// BOTH t-tiles {15-k, k} sequentially -> every block is exactly 34 k-tiles.
// (r10's work-sum balancing still left XCD0 CUs with a 32-k-tile critical path
// at 2-way parallelism -- measured OccupancyPercent 17.5% from the drain tail.
// Uniform block length is the correct invariant.) 2 blocks/CU, no RS VALU tax
// (r10: VALUBusy 29% > MfmaUtil 12% from the in-loop row-sum; now deleted).
__global__ __launch_bounds__(256, 4) void pv_gemm(
    const unsigned short* __restrict__ P, const unsigned short* __restrict__ Vt,
    const float* __restrict__ l, float* __restrict__ out)
{
    const int L = blockIdx.x;
    const int k = L & 7, j = L >> 3;          // j in [0,64)
    const int b = j >> 4;
    const int n0 = (j & 15) * 64;             // d tile (64 wide)

    __shared__ unsigned short As[128 * 64];
    __shared__ unsigned short Bs[64 * 64];

    const int lane = threadIdx.x & 63, wave = threadIdx.x >> 6;
    const int wm = (wave >> 1) * 64, wn = (wave & 1) * 32;
    const int fr = lane & 15, fq = lane >> 4;
    float* ob = out + (size_t)b * T_ * C_;
    const float* lb = l + (size_t)b * T_;

    #pragma unroll
    for (int phase = 0; phase < 2; phase++){
        const int ti = phase ? k : (15 - k);  // long tile first
        const int t0 = ti * 128;
        const int kTiles = 2 * (ti + 1);      // causal: keys s < t0+128

        floatx4 acc[4][2];
        #pragma unroll
        for (int i = 0; i < 4; i++)
            #pragma unroll
            for (int jj = 0; jj < 2; jj++) acc[i][jj] = (floatx4){0.f,0.f,0.f,0.f};
        gemm_core<64, 32>(P + (size_t)b * T_ * T_, Vt + (size_t)b * C_ * T_,
                          T_, T_, t0, n0, kTiles, As, Bs, acc);

        #pragma unroll
        for (int i = 0; i < 4; i++){
            float inv[4];
            #pragma unroll
            for (int r2 = 0; r2 < 4; r2++)
                inv[r2] = 1.f / lb[t0 + wm + i*16 + fq*4 + r2];
            #pragma unroll
            for (int jj = 0; jj < 2; jj++)
                #pragma unroll
                for (int r2 = 0; r2 < 4; r2++){
                    int t = t0 + wm + i*16 + fq*4 + r2;
                    int d = n0 + wn + jj*16 + fr;
                    ob[(size_t)t * C_ + d] = acc[i][jj][r2] * inv[r2];
                }
        }
    }
}

extern "C" void kernel_launch(void* const* d_in, const int* in_sizes, int n_in,
                              void* d_out, int out_size, void* d_ws, size_t ws_size,
                              hipStream_t stream)
{
    const float* x  = (const float*)d_in[0];
    const float* Wq = (const float*)d_in[1];
    const float* Wk = (const float*)d_in[2];
    const float* Wv = (const float*)d_in[3];
    float* out = (float*)d_out;

    // ws layout (bf16 elems): Qb | Kb | Vt | P | l(fp32). xb/Wb alias P's region
    // (written by cast, read by proj, then overwritten by score_gemm -- stream-ordered;
    // l lies beyond P's 33.5 MB so it never aliases xb/Wb).
    unsigned short* Qb = (unsigned short*)d_ws;
    unsigned short* Kb = Qb + (size_t)M_ * C_;
    unsigned short* Vt = Kb + (size_t)M_ * C_;
    unsigned short* P  = Vt + (size_t)M_ * C_;
    float* l = (float*)(P + (size_t)M_ * T_);
    unsigned short* xb = P;
    unsigned short* Wb = P + (size_t)M_ * C_;

    cast_all<<<(NX_ + 3 * NW_ + 255) / 256, 256, 0, stream>>>(x, Wq, Wk, Wv, xb, Wb);
    hipMemsetAsync(l, 0, (size_t)M_ * sizeof(float), stream);
    proj_gemm <<<1536, 256, 0, stream>>>(xb, Wb, Qb, Kb, Vt);
    score_gemm<<<1088, 256, 0, stream>>>(Qb, Kb, P, l);
    pv_gemm   <<<512,  256, 0, stream>>>(P, Vt, l, out);
}